// Round 3
// baseline (522.659 us; speedup 1.0000x reference)
//
#include <hip/hip_runtime.h>
#include <hip/hip_bf16.h>
#include <stdint.h>

// ---------------------------------------------------------------------------
// Swin-V2 window attention, MI355X (gfx950).
// Pipeline: cvt(x,qkv_w,proj_w) -> cpb_tab -> bias_gather ->
//           qkv GEMM (fused bias+cos-norm+scale, bf16 outputs, v transposed) ->
//           fused attention (flash-style, per (b,h) block) ->
//           proj GEMM (+bias) -> d_out fp32
// All matmuls: v_mfma_f32_16x16x32_bf16, fp32 accumulate.
// R1 hardening: alignas(16) LDS; o1b aliased onto xb; ws_size guard.
// R2: identical resubmit (R2 failure was GPU acquisition timeout, not kernel).
// ---------------------------------------------------------------------------

typedef __attribute__((ext_vector_type(4))) float f32x4;
typedef __attribute__((ext_vector_type(8))) short short8;

#define DIM   384
#define HEADS 12
#define NTOK  343
#define NPAD  352            // 22*16
#define BW    64             // windows*batch
#define MROWS (BW*NTOK)      // 21952
#define MPAD  22016          // 172*128
#define NN    (NTOK*NTOK)    // 117649

__device__ __forceinline__ unsigned short f2bf(float f) {
  unsigned u = __float_as_uint(f);
  u += 0x7FFF + ((u >> 16) & 1);          // RNE
  return (unsigned short)(u >> 16);
}

__device__ __forceinline__ void gload_lds16(const void* g, void* l) {
  __builtin_amdgcn_global_load_lds(
      (const __attribute__((address_space(1))) void*)g,
      (__attribute__((address_space(3))) void*)l, 16, 0, 0);
}

// --------------------------- fp32 -> bf16 convert ---------------------------
__global__ __launch_bounds__(256) void cvt_bf16(const float* __restrict__ in,
                                                unsigned short* __restrict__ out,
                                                long nvalid, long ntotal) {
  long i = ((long)blockIdx.x * 256 + threadIdx.x) * 8;
  if (i >= ntotal) return;
  short8 o;
  if (i < nvalid) {
    const float4* p = (const float4*)(in + i);
    float4 a = p[0], b = p[1];
    o[0] = (short)f2bf(a.x); o[1] = (short)f2bf(a.y);
    o[2] = (short)f2bf(a.z); o[3] = (short)f2bf(a.w);
    o[4] = (short)f2bf(b.x); o[5] = (short)f2bf(b.y);
    o[6] = (short)f2bf(b.z); o[7] = (short)f2bf(b.w);
  } else {
    o = (short8)0;                         // zero-fill M padding rows
  }
  *(short8*)(out + i) = o;
}

// --------------------------- CPB MLP (2197 x 12) ----------------------------
__global__ __launch_bounds__(64) void cpb_tab(const float* __restrict__ tbl,
                                              const float* __restrict__ w1,
                                              const float* __restrict__ b1,
                                              const float* __restrict__ w2,
                                              float* __restrict__ btab) {
  const int r = blockIdx.x, lane = threadIdx.x;
  const float t0 = tbl[r*3], t1 = tbl[r*3+1], t2 = tbl[r*3+2];
  float acc[12];
#pragma unroll
  for (int hh = 0; hh < 12; ++hh) acc[hh] = 0.f;
  for (int u = 0; u < 8; ++u) {
    const int j = lane * 8 + u;
    const float hd = fmaxf(w1[j*3]*t0 + w1[j*3+1]*t1 + w1[j*3+2]*t2 + b1[j], 0.f);
#pragma unroll
    for (int hh = 0; hh < 12; ++hh) acc[hh] += hd * w2[hh*512 + j];
  }
#pragma unroll
  for (int hh = 0; hh < 12; ++hh) {
    float v = acc[hh];
    for (int msk = 1; msk < 64; msk <<= 1) v += __shfl_xor(v, msk);
    if (lane == 0) btab[r*12 + hh] = v;
  }
}

// ------------------ bias gather: (12,343,343) = 16*sigmoid ------------------
__global__ __launch_bounds__(256) void bias_gather(const float* __restrict__ btab,
                                                   const int* __restrict__ ridx,
                                                   float* __restrict__ bfull) {
  const int blk = blockIdx.x;              // hh*343 + i
  const int hh = blk / NTOK, i = blk % NTOK;
  for (int j = threadIdx.x; j < NTOK; j += 256) {
    const int idx = ridx[i*NTOK + j];
    const float v = btab[idx*12 + hh];
    bfull[(size_t)blk*NTOK + j] = 16.f / (1.f + __expf(-v));
  }
}

// ------------------------------- GEMM (bf16) --------------------------------
// C(128x128) = A(row-major MxK) * B(N,K)^T. BK=64, 4 waves (2x2 of 64x64).
// LDS XOR swizzle (blk ^ (row&7)) applied via pre-swizzled global source so
// global_load_lds keeps a linear destination (guide rule 21).
// MODE 0: qkv epilogue (bias, cosine-norm, scale-fold, bf16 q/k + transposed v)
// MODE 1: proj epilogue (+proj_b, fp32 out)
template<int MODE>
__global__ __launch_bounds__(256, 2) void gemm_k(
    const unsigned short* __restrict__ A, const unsigned short* __restrict__ B,
    unsigned short* __restrict__ o_qn, unsigned short* __restrict__ o_kn,
    unsigned short* __restrict__ o_vT,
    const float* __restrict__ q_bias, const float* __restrict__ v_bias,
    const float* __restrict__ lsc,
    float* __restrict__ o_out, const float* __restrict__ proj_b) {
  __shared__ alignas(16) uint8_t lds[32768];   // A: [0,16K) B: [16K,32K)
  const int tid = threadIdx.x, wave = tid >> 6, lane = tid & 63;
  const int row0 = blockIdx.x * 128, col0 = blockIdx.y * 128;
  const int wm = wave & 1, wn = wave >> 1;
  const int l15 = lane & 15, lq = lane >> 4;
  f32x4 acc[4][4];
#pragma unroll
  for (int i = 0; i < 4; ++i)
#pragma unroll
    for (int j = 0; j < 4; ++j) acc[i][j] = (f32x4)0.f;

  const int stg_row = wave * 8 + (lane >> 3);
  const int srcblk = (lane & 7) ^ (lane >> 3);   // pre-swizzled source block

  for (int kt = 0; kt < 6; ++kt) {
    const int k0 = kt * 64;
#pragma unroll
    for (int c = 0; c < 4; ++c) {
      const int row = c * 32 + stg_row;
      gload_lds16(A + (size_t)(row0 + row) * DIM + k0 + srcblk * 8,
                  lds + c * 4096 + wave * 1024);
      gload_lds16(B + (size_t)(col0 + row) * DIM + k0 + srcblk * 8,
                  lds + 16384 + c * 4096 + wave * 1024);
    }
    __syncthreads();
#pragma unroll
    for (int s = 0; s < 2; ++s) {
      short8 af[4], bfr[4];
#pragma unroll
      for (int i = 0; i < 4; ++i) {
        const int r = wm * 64 + i * 16 + l15;
        af[i] = *(const short8*)(lds + r * 128 + (((s * 4) | lq) ^ (r & 7)) * 16);
        const int cc = wn * 64 + i * 16 + l15;
        bfr[i] = *(const short8*)(lds + 16384 + cc * 128 + (((s * 4) | lq) ^ (cc & 7)) * 16);
      }
#pragma unroll
      for (int i = 0; i < 4; ++i)
#pragma unroll
        for (int j = 0; j < 4; ++j)
          acc[i][j] = __builtin_amdgcn_mfma_f32_16x16x32_bf16(af[i], bfr[j], acc[i][j], 0, 0, 0);
    }
    __syncthreads();
  }

  if (MODE == 0) {
    // C cols = [q(0:384) | k(384:768) | v(768:1152)]; each 32-col chunk = one head slice
#pragma unroll
    for (int i = 0; i < 4; ++i) {
      const int gr0 = row0 + wm * 64 + i * 16 + lq * 4;
#pragma unroll
      for (int p = 0; p < 2; ++p) {
        f32x4 c0 = acc[i][2 * p], c1 = acc[i][2 * p + 1];
        const int gcb = col0 + wn * 64 + p * 32;
        const int which = gcb / DIM, rem = gcb % DIM, hh = rem / 32;
        float b0 = 0.f, b1 = 0.f;
        if (which == 0) { b0 = q_bias[rem + l15]; b1 = q_bias[rem + l15 + 16]; }
        else if (which == 2) { b0 = v_bias[rem + l15]; b1 = v_bias[rem + l15 + 16]; }
#pragma unroll
        for (int r = 0; r < 4; ++r) { c0[r] += b0; c1[r] += b1; }
        float mult[4] = {1.f, 1.f, 1.f, 1.f};
        if (which < 2) {                     // cosine-norm q,k (row = 32 cols in this chunk)
          f32x4 ss;
#pragma unroll
          for (int r = 0; r < 4; ++r) ss[r] = c0[r] * c0[r] + c1[r] * c1[r];
#pragma unroll
          for (int msk = 1; msk < 16; msk <<= 1) {
#pragma unroll
            for (int r = 0; r < 4; ++r) ss[r] += __shfl_xor(ss[r], msk);
          }
          float sc = 1.f;
          if (which == 0) sc = __expf(fminf(lsc[hh], 4.6051701860f));  // fold scale into q
#pragma unroll
          for (int r = 0; r < 4; ++r) mult[r] = sc / fmaxf(sqrtf(ss[r]), 1e-12f);
        }
#pragma unroll
        for (int r = 0; r < 4; ++r) {
          const int gr = gr0 + r;
          if (gr >= MROWS) continue;
          const int b = gr / NTOK, nt = gr % NTOK;
          const unsigned short v0 = f2bf(c0[r] * mult[r]);
          const unsigned short v1 = f2bf(c1[r] * mult[r]);
          if (which == 0) {
            const size_t base = ((size_t)(b * HEADS + hh) * NTOK + nt) * 32 + l15;
            o_qn[base] = v0; o_qn[base + 16] = v1;
          } else if (which == 1) {
            const size_t base = ((size_t)(b * HEADS + hh) * NTOK + nt) * 32 + l15;
            o_kn[base] = v0; o_kn[base + 16] = v1;
          } else {                            // v transposed: (b,h,32,NPAD)
            const size_t base = ((size_t)(b * HEADS + hh) * 32 + l15) * NPAD + nt;
            o_vT[base] = v0; o_vT[base + (size_t)16 * NPAD] = v1;
          }
        }
      }
    }
  } else {
#pragma unroll
    for (int i = 0; i < 4; ++i) {
      const int gr0 = row0 + wm * 64 + i * 16 + lq * 4;
#pragma unroll
      for (int j = 0; j < 4; ++j) {
        const int gc = col0 + wn * 64 + j * 16 + l15;
        const float pb = proj_b[gc];
#pragma unroll
        for (int r = 0; r < 4; ++r) {
          const int gr = gr0 + r;
          if (gr < MROWS) o_out[(size_t)gr * DIM + gc] = acc[i][j][r] + pb;
        }
      }
    }
  }
}

// ------------------------------- attention ---------------------------------
// 1 block = 1 (window b, head h). kn (352x32, rows padded to 80B) + v^T
// (32x352, rows padded to 720B) staged in LDS; 4 independent waves, each owns
// 16 q-rows per tile; flash-style online softmax over 11 k-chunks of 32.
__global__ __launch_bounds__(256, 2) void attn_k(
    const unsigned short* __restrict__ qn, const unsigned short* __restrict__ kn,
    const unsigned short* __restrict__ vT, const float* __restrict__ bfull,
    const float* __restrict__ mask, unsigned short* __restrict__ out1) {
  __shared__ alignas(16) uint8_t lds[56320]; // kn:[0,28160) vT:[28160,51200) P:[51200,56320)
  const int g = blockIdx.x;
  // XCD swizzle: all 12 heads of one window land on the same XCD (mask L2-local)
  const int b = (g & 7) * 8 + (g >> 3) / HEADS;
  const int hh = (g >> 3) % HEADS;
  const int bh = b * HEADS + hh;
  const int tid = threadIdx.x;

  for (int r = tid; r < NPAD; r += 256) {
    uint4* dst = (uint4*)(lds + r * 80);
    if (r < NTOK) {
      const uint4* src = (const uint4*)(kn + ((size_t)bh * NTOK + r) * 32);
      dst[0] = src[0]; dst[1] = src[1]; dst[2] = src[2]; dst[3] = src[3];
    } else {
      uint4 z = make_uint4(0, 0, 0, 0);
      dst[0] = z; dst[1] = z; dst[2] = z; dst[3] = z;
    }
  }
  for (int c = tid; c < 32 * 44; c += 256) {
    const int d = c / 44, o = c % 44;
    *(uint4*)(lds + 28160 + d * 720 + o * 16) =
        *(const uint4*)(vT + ((size_t)bh * 32 + d) * NPAD + o * 8);
  }
  __syncthreads();

  const int wave = tid >> 6, lane = tid & 63;
  const int l15 = lane & 15, lq = lane >> 4;
  uint8_t* pbuf = lds + 51200 + wave * 1280;      // 16x32 bf16, rows padded to 80B
  const float* biasp = bfull + (size_t)hh * NN;
  const float* maskp = mask + (size_t)b * NN;

  for (int qt = wave; qt < 22; qt += 4) {
    const int q0 = qt * 16;
    int qrow = q0 + l15; if (qrow > NTOK - 1) qrow = NTOK - 1;   // clamp q-pad rows
    const short8 aq = *(const short8*)(qn + ((size_t)bh * NTOK + qrow) * 32 + lq * 8);
    f32x4 o0 = (f32x4)0.f, o1 = (f32x4)0.f;
    float mrun[4] = {-1e30f, -1e30f, -1e30f, -1e30f};
    float lrun[4] = {0.f, 0.f, 0.f, 0.f};
    const int qr0 = q0 + lq * 4;

    for (int c = 0; c < 11; ++c) {
      const int kc0 = c * 32;
      const short8 bk0 = *(const short8*)(lds + (size_t)(kc0 + l15) * 80 + lq * 16);
      const short8 bk1 = *(const short8*)(lds + (size_t)(kc0 + 16 + l15) * 80 + lq * 16);
      f32x4 s0 = __builtin_amdgcn_mfma_f32_16x16x32_bf16(aq, bk0, (f32x4)0.f, 0, 0, 0);
      f32x4 s1 = __builtin_amdgcn_mfma_f32_16x16x32_bf16(aq, bk1, (f32x4)0.f, 0, 0, 0);
      const int kca = kc0 + l15, kcb = kca + 16;
#pragma unroll
      for (int r = 0; r < 4; ++r) {
        int q = qr0 + r; if (q > NTOK - 1) q = NTOK - 1;
        const size_t ro = (size_t)q * NTOK;
        if (kca < NTOK) s0[r] += biasp[ro + kca] + maskp[ro + kca]; else s0[r] = -1e30f;
        if (kcb < NTOK) s1[r] += biasp[ro + kcb] + maskp[ro + kcb]; else s1[r] = -1e30f;
      }
      float mx[4];
#pragma unroll
      for (int r = 0; r < 4; ++r) mx[r] = fmaxf(s0[r], s1[r]);
#pragma unroll
      for (int msk = 1; msk < 16; msk <<= 1)
#pragma unroll
        for (int r = 0; r < 4; ++r) mx[r] = fmaxf(mx[r], __shfl_xor(mx[r], msk));
#pragma unroll
      for (int r = 0; r < 4; ++r) {
        const float mn = fmaxf(mrun[r], mx[r]);
        const float f = __expf(mrun[r] - mn);
        mrun[r] = mn;
        const float p0 = __expf(s0[r] - mn), p1 = __expf(s1[r] - mn);
        lrun[r] = lrun[r] * f + p0 + p1;
        o0[r] *= f; o1[r] *= f;
        unsigned short* prow = (unsigned short*)(pbuf + (lq * 4 + r) * 80);
        prow[l15] = f2bf(p0);
        prow[l15 + 16] = f2bf(p1);
      }
      const short8 ap = *(const short8*)(pbuf + l15 * 80 + lq * 16);
      const short8 bv0 = *(const short8*)(lds + 28160 + (size_t)l15 * 720 + kc0 * 2 + lq * 16);
      const short8 bv1 = *(const short8*)(lds + 28160 + (size_t)(l15 + 16) * 720 + kc0 * 2 + lq * 16);
      o0 = __builtin_amdgcn_mfma_f32_16x16x32_bf16(ap, bv0, o0, 0, 0, 0);
      o1 = __builtin_amdgcn_mfma_f32_16x16x32_bf16(ap, bv1, o1, 0, 0, 0);
    }
#pragma unroll
    for (int msk = 1; msk < 16; msk <<= 1)
#pragma unroll
      for (int r = 0; r < 4; ++r) lrun[r] += __shfl_xor(lrun[r], msk);
#pragma unroll
    for (int r = 0; r < 4; ++r) {
      const int q = qr0 + r;
      if (q < NTOK) {
        const float inv = 1.f / lrun[r];
        const size_t base = ((size_t)b * NTOK + q) * DIM + hh * 32 + l15;
        out1[base] = f2bf(o0[r] * inv);
        out1[base + 16] = f2bf(o1[r] * inv);
      }
    }
  }
}

// ------------------------------- host launch --------------------------------
extern "C" void kernel_launch(void* const* d_in, const int* in_sizes, int n_in,
                              void* d_out, int out_size, void* d_ws, size_t ws_size,
                              hipStream_t stream) {
  const float* x      = (const float*)d_in[0];
  const float* mask   = (const float*)d_in[1];
  const float* qkv_w  = (const float*)d_in[2];
  const float* q_bias = (const float*)d_in[3];
  const float* v_bias = (const float*)d_in[4];
  const float* lsc    = (const float*)d_in[5];
  const float* cpb_w1 = (const float*)d_in[6];
  const float* cpb_b1 = (const float*)d_in[7];
  const float* cpb_w2 = (const float*)d_in[8];
  const float* proj_w = (const float*)d_in[9];
  const float* proj_b = (const float*)d_in[10];
  const float* rtab   = (const float*)d_in[11];
  const int*   ridx   = (const int*)d_in[12];
  float* out = (float*)d_out;
  uint8_t* ws = (uint8_t*)d_ws;

  size_t o = 0;
  auto alloc = [&](size_t bytes) { size_t r = o; o += (bytes + 255) & ~(size_t)255; return r; };
  const size_t off_xb  = alloc((size_t)MPAD * DIM * 2);   // also reused as o1b
  const size_t off_qwb = alloc((size_t)1152 * DIM * 2);
  const size_t off_pwb = alloc((size_t)DIM * DIM * 2);
  const size_t off_qnb = alloc((size_t)BW * HEADS * NTOK * 32 * 2);
  const size_t off_knb = alloc((size_t)BW * HEADS * NTOK * 32 * 2);
  const size_t off_vTb = alloc((size_t)BW * HEADS * 32 * NPAD * 2);
  const size_t off_btab  = alloc((size_t)2197 * 12 * 4);
  const size_t off_bfull = alloc((size_t)HEADS * NN * 4);
  (void)in_sizes; (void)n_in; (void)out_size;

  if (ws_size < o) {   // diagnostic sentinel: clean fail (absmax ~= max|ref|)
    hipMemsetAsync(d_out, 0, (size_t)out_size * 4, stream);
    return;
  }

  unsigned short* xb  = (unsigned short*)(ws + off_xb);
  unsigned short* o1b = xb;                      // alias: xb dead after gemm<0>
  unsigned short* qwb = (unsigned short*)(ws + off_qwb);
  unsigned short* pwb = (unsigned short*)(ws + off_pwb);
  unsigned short* qnb = (unsigned short*)(ws + off_qnb);
  unsigned short* knb = (unsigned short*)(ws + off_knb);
  unsigned short* vTb = (unsigned short*)(ws + off_vTb);
  float* btab  = (float*)(ws + off_btab);
  float* bfull = (float*)(ws + off_bfull);

  cvt_bf16<<<(long)MPAD * DIM / 8 / 256, 256, 0, stream>>>(x, xb, (long)MROWS * DIM, (long)MPAD * DIM);
  cvt_bf16<<<1152 * DIM / 8 / 256, 256, 0, stream>>>(qkv_w, qwb, 1152L * DIM, 1152L * DIM);
  cvt_bf16<<<DIM * DIM / 8 / 256, 256, 0, stream>>>(proj_w, pwb, (long)DIM * DIM, (long)DIM * DIM);
  cpb_tab<<<2197, 64, 0, stream>>>(rtab, cpb_w1, cpb_b1, cpb_w2, btab);
  bias_gather<<<HEADS * NTOK, 256, 0, stream>>>(btab, ridx, bfull);
  gemm_k<0><<<dim3(MPAD / 128, 1152 / 128), 256, 0, stream>>>(
      xb, qwb, qnb, knb, vTb, q_bias, v_bias, lsc, nullptr, nullptr);
  attn_k<<<BW * HEADS, 256, 0, stream>>>(qnb, knb, vTb, bfull, mask, o1b);
  gemm_k<1><<<dim3(MPAD / 128, DIM / 128), 256, 0, stream>>>(
      o1b, pwb, nullptr, nullptr, nullptr, nullptr, nullptr, nullptr, out, proj_b);
}

// Round 4
// 310.583 us; speedup vs baseline: 1.6828x; 1.6828x over previous
//
#include <hip/hip_runtime.h>
#include <hip/hip_bf16.h>
#include <stdint.h>

// ---------------------------------------------------------------------------
// Swin-V2 window attention, MI355X (gfx950).
// Pipeline: cvt(x,qkv_w,proj_w) -> cpb_tab -> bias_gather(padded,log2-domain) ->
//           qkv GEMM (fused bias+cos-norm+scale*log2e, bf16 q/k + v^T) ->
//           fused attention (swapped-QK flash, 2-deep reg prefetch) ->
//           proj GEMM (+bias) -> d_out fp32
// R4: attn restructured — was latency-bound (VALUBusy 16.6%, occ 16%, 3800cy/chunk).
// ---------------------------------------------------------------------------

typedef __attribute__((ext_vector_type(4))) float f32x4;
typedef __attribute__((ext_vector_type(8))) short short8;

#define DIM   384
#define HEADS 12
#define NTOK  343
#define NPAD  352            // 22*16
#define BW    64             // windows*batch
#define MROWS (BW*NTOK)      // 21952
#define MPAD  22016          // 172*128
#define NN    (NTOK*NTOK)    // 117649
#define BPAD  352            // padded bias row length
#define LOG2E 1.44269504089f

__device__ __forceinline__ unsigned short f2bf(float f) {
  unsigned u = __float_as_uint(f);
  u += 0x7FFF + ((u >> 16) & 1);          // RNE
  return (unsigned short)(u >> 16);
}

__device__ __forceinline__ void gload_lds16(const void* g, void* l) {
  __builtin_amdgcn_global_load_lds(
      (const __attribute__((address_space(1))) void*)g,
      (__attribute__((address_space(3))) void*)l, 16, 0, 0);
}

// --------------------------- fp32 -> bf16 convert ---------------------------
__global__ __launch_bounds__(256) void cvt_bf16(const float* __restrict__ in,
                                                unsigned short* __restrict__ out,
                                                long nvalid, long ntotal) {
  long i = ((long)blockIdx.x * 256 + threadIdx.x) * 8;
  if (i >= ntotal) return;
  short8 o;
  if (i < nvalid) {
    const float4* p = (const float4*)(in + i);
    float4 a = p[0], b = p[1];
    o[0] = (short)f2bf(a.x); o[1] = (short)f2bf(a.y);
    o[2] = (short)f2bf(a.z); o[3] = (short)f2bf(a.w);
    o[4] = (short)f2bf(b.x); o[5] = (short)f2bf(b.y);
    o[6] = (short)f2bf(b.z); o[7] = (short)f2bf(b.w);
  } else {
    o = (short8)0;                         // zero-fill M padding rows
  }
  *(short8*)(out + i) = o;
}

// --------------------------- CPB MLP (2197 x 12) ----------------------------
__global__ __launch_bounds__(64) void cpb_tab(const float* __restrict__ tbl,
                                              const float* __restrict__ w1,
                                              const float* __restrict__ b1,
                                              const float* __restrict__ w2,
                                              float* __restrict__ btab) {
  const int r = blockIdx.x, lane = threadIdx.x;
  const float t0 = tbl[r*3], t1 = tbl[r*3+1], t2 = tbl[r*3+2];
  float acc[12];
#pragma unroll
  for (int hh = 0; hh < 12; ++hh) acc[hh] = 0.f;
  for (int u = 0; u < 8; ++u) {
    const int j = lane * 8 + u;
    const float hd = fmaxf(w1[j*3]*t0 + w1[j*3+1]*t1 + w1[j*3+2]*t2 + b1[j], 0.f);
#pragma unroll
    for (int hh = 0; hh < 12; ++hh) acc[hh] += hd * w2[hh*512 + j];
  }
#pragma unroll
  for (int hh = 0; hh < 12; ++hh) {
    float v = acc[hh];
    for (int msk = 1; msk < 64; msk <<= 1) v += __shfl_xor(v, msk);
    if (lane == 0) btab[r*12 + hh] = v;
  }
}

// -------- bias gather: (12,343,352 padded) = LOG2E*16*sigmoid, pad=0 --------
__global__ __launch_bounds__(256) void bias_gather(const float* __restrict__ btab,
                                                   const int* __restrict__ ridx,
                                                   float* __restrict__ bfull) {
  const int blk = blockIdx.x;              // hh*343 + i
  const int hh = blk / NTOK, i = blk % NTOK;
  for (int j = threadIdx.x; j < BPAD; j += 256) {
    float o = 0.f;
    if (j < NTOK) {
      const int idx = ridx[i*NTOK + j];
      const float v = btab[idx*12 + hh];
      o = LOG2E * 16.f / (1.f + __expf(-v));
    }
    bfull[(size_t)blk*BPAD + j] = o;
  }
}

// ------------------------------- GEMM (bf16) --------------------------------
// C(128x128) = A(row-major MxK) * B(N,K)^T. BK=64, 4 waves (2x2 of 64x64).
// LDS XOR swizzle applied via pre-swizzled global source (guide rule 21).
// MODE 0: qkv epilogue (bias, cosine-norm, scale*LOG2E fold, bf16 q/k + v^T)
// MODE 1: proj epilogue (+proj_b, fp32 out)
template<int MODE>
__global__ __launch_bounds__(256, 2) void gemm_k(
    const unsigned short* __restrict__ A, const unsigned short* __restrict__ B,
    unsigned short* __restrict__ o_qn, unsigned short* __restrict__ o_kn,
    unsigned short* __restrict__ o_vT,
    const float* __restrict__ q_bias, const float* __restrict__ v_bias,
    const float* __restrict__ lsc,
    float* __restrict__ o_out, const float* __restrict__ proj_b) {
  __shared__ alignas(16) uint8_t lds[32768];   // A: [0,16K) B: [16K,32K)
  const int tid = threadIdx.x, wave = tid >> 6, lane = tid & 63;
  const int row0 = blockIdx.x * 128, col0 = blockIdx.y * 128;
  const int wm = wave & 1, wn = wave >> 1;
  const int l15 = lane & 15, lq = lane >> 4;
  f32x4 acc[4][4];
#pragma unroll
  for (int i = 0; i < 4; ++i)
#pragma unroll
    for (int j = 0; j < 4; ++j) acc[i][j] = (f32x4)0.f;

  const int stg_row = wave * 8 + (lane >> 3);
  const int srcblk = (lane & 7) ^ (lane >> 3);   // pre-swizzled source block

  for (int kt = 0; kt < 6; ++kt) {
    const int k0 = kt * 64;
#pragma unroll
    for (int c = 0; c < 4; ++c) {
      const int row = c * 32 + stg_row;
      gload_lds16(A + (size_t)(row0 + row) * DIM + k0 + srcblk * 8,
                  lds + c * 4096 + wave * 1024);
      gload_lds16(B + (size_t)(col0 + row) * DIM + k0 + srcblk * 8,
                  lds + 16384 + c * 4096 + wave * 1024);
    }
    __syncthreads();
#pragma unroll
    for (int s = 0; s < 2; ++s) {
      short8 af[4], bfr[4];
#pragma unroll
      for (int i = 0; i < 4; ++i) {
        const int r = wm * 64 + i * 16 + l15;
        af[i] = *(const short8*)(lds + r * 128 + (((s * 4) | lq) ^ (r & 7)) * 16);
        const int cc = wn * 64 + i * 16 + l15;
        bfr[i] = *(const short8*)(lds + 16384 + cc * 128 + (((s * 4) | lq) ^ (cc & 7)) * 16);
      }
#pragma unroll
      for (int i = 0; i < 4; ++i)
#pragma unroll
        for (int j = 0; j < 4; ++j)
          acc[i][j] = __builtin_amdgcn_mfma_f32_16x16x32_bf16(af[i], bfr[j], acc[i][j], 0, 0, 0);
    }
    __syncthreads();
  }

  if (MODE == 0) {
    // C cols = [q(0:384) | k(384:768) | v(768:1152)]; each 32-col chunk = one head slice
#pragma unroll
    for (int i = 0; i < 4; ++i) {
      const int gr0 = row0 + wm * 64 + i * 16 + lq * 4;
#pragma unroll
      for (int p = 0; p < 2; ++p) {
        f32x4 c0 = acc[i][2 * p], c1 = acc[i][2 * p + 1];
        const int gcb = col0 + wn * 64 + p * 32;
        const int which = gcb / DIM, rem = gcb % DIM, hh = rem / 32;
        float b0 = 0.f, b1 = 0.f;
        if (which == 0) { b0 = q_bias[rem + l15]; b1 = q_bias[rem + l15 + 16]; }
        else if (which == 2) { b0 = v_bias[rem + l15]; b1 = v_bias[rem + l15 + 16]; }
#pragma unroll
        for (int r = 0; r < 4; ++r) { c0[r] += b0; c1[r] += b1; }
        float mult[4] = {1.f, 1.f, 1.f, 1.f};
        if (which < 2) {                     // cosine-norm q,k (row = 32 cols in this chunk)
          f32x4 ss;
#pragma unroll
          for (int r = 0; r < 4; ++r) ss[r] = c0[r] * c0[r] + c1[r] * c1[r];
#pragma unroll
          for (int msk = 1; msk < 16; msk <<= 1) {
#pragma unroll
            for (int r = 0; r < 4; ++r) ss[r] += __shfl_xor(ss[r], msk);
          }
          float sc = 1.f;
          if (which == 0)                    // fold scale AND log2(e) into q
            sc = __expf(fminf(lsc[hh], 4.6051701860f)) * LOG2E;
#pragma unroll
          for (int r = 0; r < 4; ++r) mult[r] = sc / fmaxf(sqrtf(ss[r]), 1e-12f);
        }
#pragma unroll
        for (int r = 0; r < 4; ++r) {
          const int gr = gr0 + r;
          if (gr >= MROWS) continue;
          const int b = gr / NTOK, nt = gr % NTOK;
          const unsigned short v0 = f2bf(c0[r] * mult[r]);
          const unsigned short v1 = f2bf(c1[r] * mult[r]);
          if (which == 0) {
            const size_t base = ((size_t)(b * HEADS + hh) * NTOK + nt) * 32 + l15;
            o_qn[base] = v0; o_qn[base + 16] = v1;
          } else if (which == 1) {
            const size_t base = ((size_t)(b * HEADS + hh) * NTOK + nt) * 32 + l15;
            o_kn[base] = v0; o_kn[base + 16] = v1;
          } else {                            // v transposed: (b,h,32,NPAD)
            const size_t base = ((size_t)(b * HEADS + hh) * 32 + l15) * NPAD + nt;
            o_vT[base] = v0; o_vT[base + (size_t)16 * NPAD] = v1;
          }
        }
      }
    }
  } else {
#pragma unroll
    for (int i = 0; i < 4; ++i) {
      const int gr0 = row0 + wm * 64 + i * 16 + lq * 4;
#pragma unroll
      for (int j = 0; j < 4; ++j) {
        const int gc = col0 + wn * 64 + j * 16 + l15;
        const float pb = proj_b[gc];
#pragma unroll
        for (int r = 0; r < 4; ++r) {
          const int gr = gr0 + r;
          if (gr < MROWS) o_out[(size_t)gr * DIM + gc] = acc[i][j][r] + pb;
        }
      }
    }
  }
}

// ------------------------------- attention ---------------------------------
// 1 block = 1 (window b, head h). Swapped QK^T (mfma(K,Q)) so each lane owns
// one q-row's k-slice: max/sum reduce = 2 shfl. K in LDS (80B rows); V, bias
// (padded, log2-domain), mask prefetched from global 1 chunk ahead into regs.
// LDS 33280 -> 3 blocks/CU (768 blocks = exactly 3/CU).
__global__ __launch_bounds__(256, 3) void attn_k(
    const unsigned short* __restrict__ qn, const unsigned short* __restrict__ kn,
    const unsigned short* __restrict__ vT, const float* __restrict__ bfull,
    const float* __restrict__ mask, unsigned short* __restrict__ out1) {
  __shared__ alignas(16) uint8_t lds[33280]; // kn:[0,28160) P: 4 waves x 1280
  const int g = blockIdx.x;
  // XCD swizzle: all 12 heads of one window land on the same XCD (mask L2-local)
  const int b = (g & 7) * 8 + (g >> 3) / HEADS;
  const int hh = (g >> 3) % HEADS;
  const int bh = b * HEADS + hh;
  const int tid = threadIdx.x;

  for (int r = tid; r < NPAD; r += 256) {
    uint4* dst = (uint4*)(lds + r * 80);
    if (r < NTOK) {
      const uint4* src = (const uint4*)(kn + ((size_t)bh * NTOK + r) * 32);
      dst[0] = src[0]; dst[1] = src[1]; dst[2] = src[2]; dst[3] = src[3];
    } else {
      uint4 z = make_uint4(0, 0, 0, 0);
      dst[0] = z; dst[1] = z; dst[2] = z; dst[3] = z;
    }
  }
  __syncthreads();

  const int wave = tid >> 6, lane = tid & 63;
  const int l15 = lane & 15, lq = lane >> 4;
  uint8_t* pbuf = lds + 28160 + wave * 1280;      // 16 rows x 80B (bf16 P)

  const unsigned short* vrow0 = vT + ((size_t)bh * 32 + l15) * NPAD;      // d=l15
  const unsigned short* vrow1 = vT + ((size_t)bh * 32 + 16 + l15) * NPAD; // d=l15+16

  for (int qt = wave; qt < 22; qt += 4) {
    const int q0 = qt * 16;
    const int qc = min(q0 + l15, NTOK - 1);     // clamp pad q-rows
    const short8 aq = *(const short8*)(qn + ((size_t)bh * NTOK + qc) * 32 + lq * 8);
    const float* brow = bfull + ((size_t)hh * NTOK + qc) * BPAD;
    const float* mrow = mask + (size_t)b * NN + (size_t)qc * NTOK;

    f32x4 o0 = (f32x4)0.f, o1 = (f32x4)0.f;
    float m_run = -1e30f, l_run = 0.f;

    f32x4 pf_ba[2], pf_bb[2];
    float pf_ma[2][4], pf_mb[2][4];
    short8 pf_v0[2], pf_v1[2], pf_k0[2], pf_k1[2];

    // prefetch chunk 0
    pf_ba[0] = *(const f32x4*)(brow + lq * 4);
    pf_bb[0] = *(const f32x4*)(brow + 16 + lq * 4);
#pragma unroll
    for (int r = 0; r < 4; ++r) {
      pf_ma[0][r] = mrow[lq * 4 + r];
      pf_mb[0][r] = mrow[16 + lq * 4 + r];
    }
    pf_v0[0] = *(const short8*)(vrow0 + lq * 8);
    pf_v1[0] = *(const short8*)(vrow1 + lq * 8);
    pf_k0[0] = *(const short8*)(lds + (l15) * 80 + lq * 16);
    pf_k1[0] = *(const short8*)(lds + (16 + l15) * 80 + lq * 16);

#pragma unroll
    for (int c = 0; c < 11; ++c) {
      const int cur = c & 1, nxt = cur ^ 1;
      if (c < 10) {                         // issue next-chunk loads early
        const int kc = (c + 1) * 32;
        pf_ba[nxt] = *(const f32x4*)(brow + kc + lq * 4);
        pf_bb[nxt] = *(const f32x4*)(brow + kc + 16 + lq * 4);
#pragma unroll
        for (int r = 0; r < 4; ++r) {
          pf_ma[nxt][r] = mrow[kc + lq * 4 + r];
          const int kk = kc + 16 + lq * 4 + r;
          pf_mb[nxt][r] = mrow[(c == 9 && kk >= NTOK) ? 0 : kk];  // clamp OOB (masked later)
        }
        pf_v0[nxt] = *(const short8*)(vrow0 + kc + lq * 8);
        pf_v1[nxt] = *(const short8*)(vrow1 + kc + lq * 8);
        pf_k0[nxt] = *(const short8*)(lds + (kc + l15) * 80 + lq * 16);
        pf_k1[nxt] = *(const short8*)(lds + (kc + 16 + l15) * 80 + lq * 16);
      }
      // swapped QK^T: D[k = lq*4+r (+16), q = l15]
      f32x4 s0 = __builtin_amdgcn_mfma_f32_16x16x32_bf16(pf_k0[cur], aq, (f32x4)0.f, 0, 0, 0);
      f32x4 s1 = __builtin_amdgcn_mfma_f32_16x16x32_bf16(pf_k1[cur], aq, (f32x4)0.f, 0, 0, 0);
#pragma unroll
      for (int r = 0; r < 4; ++r) {
        s0[r] = s0[r] + pf_ba[cur][r] + pf_ma[cur][r] * LOG2E;
        s1[r] = s1[r] + pf_bb[cur][r] + pf_mb[cur][r] * LOG2E;
      }
      if (c == 10) {
#pragma unroll
        for (int r = 0; r < 4; ++r)
          if (336 + lq * 4 + r >= NTOK) s1[r] = -1e30f;
      }
      // row max over this chunk's 32 k: 7 local + lanes xor16/xor32
      float mx = fmaxf(fmaxf(fmaxf(s0[0], s0[1]), fmaxf(s0[2], s0[3])),
                       fmaxf(fmaxf(s1[0], s1[1]), fmaxf(s1[2], s1[3])));
      mx = fmaxf(mx, __shfl_xor(mx, 16));
      mx = fmaxf(mx, __shfl_xor(mx, 32));
      const float mn = fmaxf(m_run, mx);
      const float f = exp2f(m_run - mn);
      m_run = mn;
      float p0[4], p1[4], psum = 0.f;
#pragma unroll
      for (int r = 0; r < 4; ++r) {
        p0[r] = exp2f(s0[r] - mn);
        p1[r] = exp2f(s1[r] - mn);
        psum += p0[r] + p1[r];
      }
      l_run = l_run * f + psum;
      // broadcast rescale factor to o-holder lanes (o rows q = lq*4+r)
      float fr[4];
#pragma unroll
      for (int r = 0; r < 4; ++r) fr[r] = __shfl(f, lq * 4 + r);
#pragma unroll
      for (int r = 0; r < 4; ++r) { o0[r] *= fr[r]; o1[r] *= fr[r]; }
      // pack P row (q=l15) to bf16, bounce through LDS into A-operand layout
      const unsigned uu0 = ((unsigned)f2bf(p0[1]) << 16) | f2bf(p0[0]);
      const unsigned uu1 = ((unsigned)f2bf(p0[3]) << 16) | f2bf(p0[2]);
      const unsigned uu2 = ((unsigned)f2bf(p1[1]) << 16) | f2bf(p1[0]);
      const unsigned uu3 = ((unsigned)f2bf(p1[3]) << 16) | f2bf(p1[2]);
      uint2* w0 = (uint2*)(pbuf + l15 * 80 + lq * 8);
      uint2* w1 = (uint2*)(pbuf + l15 * 80 + 32 + lq * 8);
      *w0 = make_uint2(uu0, uu1);
      *w1 = make_uint2(uu2, uu3);
      const short8 pfrag = *(const short8*)(pbuf + l15 * 80 + lq * 16);
      o0 = __builtin_amdgcn_mfma_f32_16x16x32_bf16(pfrag, pf_v0[cur], o0, 0, 0, 0);
      o1 = __builtin_amdgcn_mfma_f32_16x16x32_bf16(pfrag, pf_v1[cur], o1, 0, 0, 0);
    }
    l_run += __shfl_xor(l_run, 16);
    l_run += __shfl_xor(l_run, 32);
    const float invl = 1.f / l_run;
    float ir[4];
#pragma unroll
    for (int r = 0; r < 4; ++r) ir[r] = __shfl(invl, lq * 4 + r);
#pragma unroll
    for (int r = 0; r < 4; ++r) {
      const int q = q0 + lq * 4 + r;
      if (q < NTOK) {
        const size_t base = ((size_t)b * NTOK + q) * DIM + hh * 32 + l15;
        out1[base]      = f2bf(o0[r] * ir[r]);
        out1[base + 16] = f2bf(o1[r] * ir[r]);
      }
    }
  }
}

// ------------------------------- host launch --------------------------------
extern "C" void kernel_launch(void* const* d_in, const int* in_sizes, int n_in,
                              void* d_out, int out_size, void* d_ws, size_t ws_size,
                              hipStream_t stream) {
  const float* x      = (const float*)d_in[0];
  const float* mask   = (const float*)d_in[1];
  const float* qkv_w  = (const float*)d_in[2];
  const float* q_bias = (const float*)d_in[3];
  const float* v_bias = (const float*)d_in[4];
  const float* lsc    = (const float*)d_in[5];
  const float* cpb_w1 = (const float*)d_in[6];
  const float* cpb_b1 = (const float*)d_in[7];
  const float* cpb_w2 = (const float*)d_in[8];
  const float* proj_w = (const float*)d_in[9];
  const float* proj_b = (const float*)d_in[10];
  const float* rtab   = (const float*)d_in[11];
  const int*   ridx   = (const int*)d_in[12];
  float* out = (float*)d_out;
  uint8_t* ws = (uint8_t*)d_ws;

  size_t o = 0;
  auto alloc = [&](size_t bytes) { size_t r = o; o += (bytes + 255) & ~(size_t)255; return r; };
  const size_t off_xb  = alloc((size_t)MPAD * DIM * 2);   // also reused as o1b
  const size_t off_qwb = alloc((size_t)1152 * DIM * 2);
  const size_t off_pwb = alloc((size_t)DIM * DIM * 2);
  const size_t off_qnb = alloc((size_t)BW * HEADS * NTOK * 32 * 2);
  const size_t off_knb = alloc((size_t)BW * HEADS * NTOK * 32 * 2);
  const size_t off_vTb = alloc((size_t)BW * HEADS * 32 * NPAD * 2);
  const size_t off_btab  = alloc((size_t)2197 * 12 * 4);
  const size_t off_bfull = alloc((size_t)HEADS * NTOK * BPAD * 4);
  (void)in_sizes; (void)n_in; (void)out_size;

  if (ws_size < o) {   // diagnostic sentinel: clean fail (absmax ~= max|ref|)
    hipMemsetAsync(d_out, 0, (size_t)out_size * 4, stream);
    return;
  }

  unsigned short* xb  = (unsigned short*)(ws + off_xb);
  unsigned short* o1b = xb;                      // alias: xb dead after gemm<0>
  unsigned short* qwb = (unsigned short*)(ws + off_qwb);
  unsigned short* pwb = (unsigned short*)(ws + off_pwb);
  unsigned short* qnb = (unsigned short*)(ws + off_qnb);
  unsigned short* knb = (unsigned short*)(ws + off_knb);
  unsigned short* vTb = (unsigned short*)(ws + off_vTb);
  float* btab  = (float*)(ws + off_btab);
  float* bfull = (float*)(ws + off_bfull);

  cvt_bf16<<<(long)MPAD * DIM / 8 / 256, 256, 0, stream>>>(x, xb, (long)MROWS * DIM, (long)MPAD * DIM);
  cvt_bf16<<<1152 * DIM / 8 / 256, 256, 0, stream>>>(qkv_w, qwb, 1152L * DIM, 1152L * DIM);
  cvt_bf16<<<DIM * DIM / 8 / 256, 256, 0, stream>>>(proj_w, pwb, (long)DIM * DIM, (long)DIM * DIM);
  cpb_tab<<<2197, 64, 0, stream>>>(rtab, cpb_w1, cpb_b1, cpb_w2, btab);
  bias_gather<<<HEADS * NTOK, 256, 0, stream>>>(btab, ridx, bfull);
  gemm_k<0><<<dim3(MPAD / 128, 1152 / 128), 256, 0, stream>>>(
      xb, qwb, qnb, knb, vTb, q_bias, v_bias, lsc, nullptr, nullptr);
  attn_k<<<BW * HEADS, 256, 0, stream>>>(qnb, knb, vTb, bfull, mask, o1b);
  gemm_k<1><<<dim3(MPAD / 128, DIM / 128), 256, 0, stream>>>(
      o1b, pwb, nullptr, nullptr, nullptr, nullptr, nullptr, nullptr, out, proj_b);
}